// Round 13
// baseline (94.026 us; speedup 1.0000x reference)
//
#include <hip/hip_runtime.h>
#include <hip/hip_fp16.h>

// Separable 3D Gaussian blur (sigma=1, truncate=3 -> 7 taps), SAME zero padding.
// (N=2, D=160, H=160, W=160, C=4) float32 == float4 over C.
// Round 13 = R10 base (CHUNK=16, 1000 blocks, XCD swizzle, dbuf f32 raw) with
// ONE barrier per slice via cross-slice software pipelining:
//   per iter k (slice s): barrier; then 3 independent phases:
//     W-blur raw[k&1] -> wb[k&1]      (slice s)
//     H-blur wb[(k-1)&1] -> rings     (slice s-1, one behind)
//     commit raw[(k+1)&1] <- prefetch (slice s+1)
//   Every same-buffer read/write pair is separated by >=1 lgkm-draining
//   barrier; W-reads and H-reads are independent -> latencies overlap.
// wb stored fp16 (R9-validated accuracy, absmax 3.9e-3 << 1.7e-2) to keep
// LDS at 39.4 KB; raw stays f32 (no cvt on the stage critical path); rings f32.

#define THT 16
#define TWT 32
#define CHUNK 16
#define DIM 160
#define SLICE (DIM * DIM)
#define RAWN (22 * 38)
#define NBLK 1000          // 2*10*5*10 = 8 XCDs x 125

#define W0 0.004433048f
#define W1 0.054005582f
#define W2 0.242036229f
#define W3 0.399050300f

__device__ __forceinline__ float4 blur7(float4 a0, float4 a1, float4 a2, float4 a3,
                                        float4 a4, float4 a5, float4 a6) {
    float4 r;
    r.x = W0 * (a0.x + a6.x) + W1 * (a1.x + a5.x) + W2 * (a2.x + a4.x) + W3 * a3.x;
    r.y = W0 * (a0.y + a6.y) + W1 * (a1.y + a5.y) + W2 * (a2.y + a4.y) + W3 * a3.y;
    r.z = W0 * (a0.z + a6.z) + W1 * (a1.z + a5.z) + W2 * (a2.z + a4.z) + W3 * a3.z;
    r.w = W0 * (a0.w + a6.w) + W1 * (a1.w + a5.w) + W2 * (a2.w + a4.w) + W3 * a3.w;
    return r;
}

__device__ __forceinline__ unsigned h2u(__half2 h) { return *reinterpret_cast<const unsigned*>(&h); }

__device__ __forceinline__ uint2 pack_h4(float4 v) {
    __half2 a = __floats2half2_rn(v.x, v.y);
    __half2 b = __floats2half2_rn(v.z, v.w);
    uint2 r; r.x = h2u(a); r.y = h2u(b); return r;
}
__device__ __forceinline__ float4 unpack_h4(uint2 u) {
    float2 a = __half22float2(*reinterpret_cast<const __half2*>(&u.x));
    float2 b = __half22float2(*reinterpret_cast<const __half2*>(&u.y));
    return make_float4(a.x, a.y, b.x, b.y);
}

// Workgroup barrier with LDS visibility but NO vmcnt(0) drain -> prefetched
// global loads stay in flight across it.
__device__ __forceinline__ void lds_barrier() {
    asm volatile("s_waitcnt lgkmcnt(0)" ::: "memory");
    __builtin_amdgcn_s_barrier();
}

__global__ __launch_bounds__(256, 4)
void gauss3d_fused(const float4* __restrict__ in, float4* __restrict__ out) {
    // XCD-chunked bijective swizzle: 1000 = 8 * 125 exactly.
    int work = (blockIdx.x & 7) * (NBLK / 8) + (blockIdx.x >> 3);
    const int tw    = work % (DIM / TWT);   work /= (DIM / TWT);   // 5
    const int th    = work % (DIM / THT);   work /= (DIM / THT);   // 10
    const int chunk = work % (DIM / CHUNK); work /= (DIM / CHUNK); // 10
    const int n     = work;                                        // 2

    const int h0 = th * THT;
    const int w0 = tw * TWT;
    const int d0 = chunk * CHUNK;

    __shared__ float4 raw[2][22][39];  // halo 22(H) x 38(W) f32, odd pad, dbuf
    __shared__ uint2  wb[2][22][34];   // W-blurred 22 x 32 f16x4, dbuf

    const int tid = threadIdx.x;
    const size_t nbase = (size_t)n * DIM * SLICE;
    const float4 z = make_float4(0.f, 0.f, 0.f, 0.f);

    // ---- stage constants: 836 halo f4 over 256 threads (<=4 slots) ----
    int  soff[4], rbidx[4];
    bool sok[4];
    #pragma unroll
    for (int s = 0; s < 4; ++s) {
        const int i = tid + 256 * s;
        const bool has = (i < RAWN);
        const int rr = has ? (i / 38) : 0, cc = has ? (i % 38) : 0;
        const int gh = h0 + rr - 3, gw = w0 + cc - 3;
        const bool ok = has && gh >= 0 && gh < DIM && gw >= 0 && gw < DIM;
        soff[s]  = ok ? (gh * DIM + gw) : 0;
        sok[s]   = ok;
        rbidx[s] = rr * 39 + cc;
    }
    const bool shas3 = (tid + 768 < RAWN);

    // ---- W-blur workers: 176 = 22 rows x 8 groups of 4 cols ----
    const bool isW = (tid < 176);
    const int wr  = tid >> 3;        // 0..21
    const int wc0 = (tid & 7) * 4;   // 0,4,...,28

    // ---- H-blur: 256 threads = 8 H-pairs x 32 cols ----
    const int hp = tid >> 5;         // 0..7 -> output rows 2hp, 2hp+1
    const int lw = tid & 31;         // 0..31

    float4 pf0, pf1, pf2, pf3;
    float4 a0 = z, a1 = z, a2 = z, a3 = z, a4 = z, a5 = z, a6 = z;  // ring row 2hp
    float4 b0 = z, b1 = z, b2 = z, b3 = z, b4 = z, b5 = z, b6 = z;  // ring row 2hp+1

#define PREFETCH(DSL)                                                        \
    do {                                                                     \
        const int _d = (DSL);                                                \
        const bool _inr = (_d >= 0) && (_d < DIM);                           \
        const float4* _s = in + nbase + (size_t)(_inr ? _d : 0) * SLICE;     \
        pf0 = (_inr && sok[0]) ? _s[soff[0]] : z;                            \
        pf1 = (_inr && sok[1]) ? _s[soff[1]] : z;                            \
        pf2 = (_inr && sok[2]) ? _s[soff[2]] : z;                            \
        pf3 = (_inr && sok[3]) ? _s[soff[3]] : z;                            \
    } while (0)

#define COMMIT(BUF)                                                          \
    do {                                                                     \
        float4* rb = &raw[BUF][0][0];                                        \
        rb[rbidx[0]] = pf0;                                                  \
        rb[rbidx[1]] = pf1;                                                  \
        rb[rbidx[2]] = pf2;                                                  \
        if (shas3) rb[rbidx[3]] = pf3;                                       \
    } while (0)

    // ---- prologue: slice d0-3 into raw[0]; prefetch d0-2 ----
    PREFETCH(d0 - 3);
    COMMIT(0);
    PREFETCH(d0 - 2);

    // slices span d0-3 .. d0+CHUNK+2 (22 slices); loop k=0..CHUNK+6 (23 iters)
    for (int k = 0; k <= CHUNK + 6; ++k) {
        const int s = d0 - 3 + k;          // W-phase slice
        const int buf = k & 1;

        lds_barrier();  // raw[buf] (slice s) and wb[buf^1] (slice s-1) visible;
                        // prior reads of raw[buf^1] / wb[buf] drained.

        // W-phase: slice s -> wb[buf] (fp16)
        if (s <= d0 + CHUNK + 2) {          // wave-uniform
            if (isW) {
                float4 rv0 = raw[buf][wr][wc0 + 0];
                float4 rv1 = raw[buf][wr][wc0 + 1];
                float4 rv2 = raw[buf][wr][wc0 + 2];
                float4 rv3 = raw[buf][wr][wc0 + 3];
                float4 rv4 = raw[buf][wr][wc0 + 4];
                float4 rv5 = raw[buf][wr][wc0 + 5];
                float4 rv6 = raw[buf][wr][wc0 + 6];
                float4 rv7 = raw[buf][wr][wc0 + 7];
                float4 rv8 = raw[buf][wr][wc0 + 8];
                float4 rv9 = raw[buf][wr][wc0 + 9];
                wb[buf][wr][wc0 + 0] = pack_h4(blur7(rv0, rv1, rv2, rv3, rv4, rv5, rv6));
                wb[buf][wr][wc0 + 1] = pack_h4(blur7(rv1, rv2, rv3, rv4, rv5, rv6, rv7));
                wb[buf][wr][wc0 + 2] = pack_h4(blur7(rv2, rv3, rv4, rv5, rv6, rv7, rv8));
                wb[buf][wr][wc0 + 3] = pack_h4(blur7(rv3, rv4, rv5, rv6, rv7, rv8, rv9));
            }
        }

        // H-phase: slice s-1 from wb[buf^1] -> rings -> output (s-1)-3
        if (k >= 1) {                       // wave-uniform
            const int pb = buf ^ 1;
            float4 c0 = unpack_h4(wb[pb][2 * hp + 0][lw]);
            float4 c1 = unpack_h4(wb[pb][2 * hp + 1][lw]);
            float4 c2 = unpack_h4(wb[pb][2 * hp + 2][lw]);
            float4 c3 = unpack_h4(wb[pb][2 * hp + 3][lw]);
            float4 c4 = unpack_h4(wb[pb][2 * hp + 4][lw]);
            float4 c5 = unpack_h4(wb[pb][2 * hp + 5][lw]);
            float4 c6 = unpack_h4(wb[pb][2 * hp + 6][lw]);
            float4 c7 = unpack_h4(wb[pb][2 * hp + 7][lw]);
            float4 va = blur7(c0, c1, c2, c3, c4, c5, c6);
            float4 vb = blur7(c1, c2, c3, c4, c5, c6, c7);
            a0 = a1; a1 = a2; a2 = a3; a3 = a4; a4 = a5; a5 = a6; a6 = va;
            b0 = b1; b1 = b2; b2 = b3; b3 = b4; b4 = b5; b5 = b6; b6 = vb;

            const int dout = s - 4;         // (s-1) - 3
            if (dout >= d0 && dout < d0 + CHUNK) {
                float4 oa = blur7(a0, a1, a2, a3, a4, a5, a6);
                float4 ob = blur7(b0, b1, b2, b3, b4, b5, b6);
                const size_t base = nbase + (size_t)dout * SLICE;
                out[base + (size_t)(h0 + 2 * hp + 0) * DIM + (w0 + lw)] = oa;
                out[base + (size_t)(h0 + 2 * hp + 1) * DIM + (w0 + lw)] = ob;
            }
        }

        // commit slice s+1 into raw[buf^1]; its previous contents (slice s-1)
        // were last read by W-phase in iter k-1, drained at this barrier.
        if (s + 1 <= d0 + CHUNK + 2) {      // wave-uniform
            COMMIT(buf ^ 1);
            if (s + 2 <= d0 + CHUNK + 2) PREFETCH(s + 2);
        }
    }
#undef PREFETCH
#undef COMMIT
}

extern "C" void kernel_launch(void* const* d_in, const int* in_sizes, int n_in,
                              void* d_out, int out_size, void* d_ws, size_t ws_size,
                              hipStream_t stream) {
    const float4* in = (const float4*)d_in[0];
    float4* out = (float4*)d_out;
    gauss3d_fused<<<NBLK, 256, 0, stream>>>(in, out);
}

// Round 14
// 91.851 us; speedup vs baseline: 1.0237x; 1.0237x over previous
//
#include <hip/hip_runtime.h>

// Separable 3D Gaussian blur (sigma=1, truncate=3 -> 7 taps), SAME zero padding.
// (N=2, D=160, H=160, W=160, C=4) float32 == float4 over C.
// Round 14 = R11 (best: 79.2us) + dependent-chain reduction, skeleton intact:
//  - #pragma unroll 4 on the 16-slice loop: the dual 7-deep float4 D-rings
//    (28 v_mov/thread/slice of pure chain-serial VALU) become register
//    renaming inside each unrolled group.
//  - output address maintained by increment, not per-slice 64-bit recompute.
// Unchanged from R11: tile 16x32, CHUNK=10, 1600 blocks, XCD-chunked swizzle,
// single-buffered f32 raw(22x39)+wb(22x33) = 25.6KB, 176 W-workers x (10 b128
// reads -> 4 outputs), H-pairs, prefetch-1, 2 lgkmcnt-only barriers,
// launch_bounds(256,4). Spill canary: WRITE_SIZE must stay ~134MB.

#define THT 16
#define TWT 32
#define CHUNK 10
#define DIM 160
#define SLICE (DIM * DIM)
#define RAWN (22 * 38)
#define NBLK 1600          // 2*10*5*16 = 8 XCDs x 200

#define W0 0.004433048f
#define W1 0.054005582f
#define W2 0.242036229f
#define W3 0.399050300f

__device__ __forceinline__ float4 blur7(float4 a0, float4 a1, float4 a2, float4 a3,
                                        float4 a4, float4 a5, float4 a6) {
    float4 r;
    r.x = W0 * (a0.x + a6.x) + W1 * (a1.x + a5.x) + W2 * (a2.x + a4.x) + W3 * a3.x;
    r.y = W0 * (a0.y + a6.y) + W1 * (a1.y + a5.y) + W2 * (a2.y + a4.y) + W3 * a3.y;
    r.z = W0 * (a0.z + a6.z) + W1 * (a1.z + a5.z) + W2 * (a2.z + a4.z) + W3 * a3.z;
    r.w = W0 * (a0.w + a6.w) + W1 * (a1.w + a5.w) + W2 * (a2.w + a4.w) + W3 * a3.w;
    return r;
}

// Workgroup barrier with LDS visibility but NO vmcnt(0) drain -> prefetched
// global loads stay in flight across it.
__device__ __forceinline__ void lds_barrier() {
    asm volatile("s_waitcnt lgkmcnt(0)" ::: "memory");
    __builtin_amdgcn_s_barrier();
}

__global__ __launch_bounds__(256, 4)
void gauss3d_fused(const float4* __restrict__ in, float4* __restrict__ out) {
    // XCD-chunked bijective swizzle: 1600 = 8 * 200 exactly.
    int work = (blockIdx.x & 7) * (NBLK / 8) + (blockIdx.x >> 3);
    const int tw    = work % (DIM / TWT);   work /= (DIM / TWT);   // 5
    const int th    = work % (DIM / THT);   work /= (DIM / THT);   // 10
    const int chunk = work % (DIM / CHUNK); work /= (DIM / CHUNK); // 16
    const int n     = work;                                        // 2

    const int h0 = th * THT;
    const int w0 = tw * TWT;
    const int d0 = chunk * CHUNK;

    __shared__ float4 raw[22][39];  // halo 22(H) x 38(W), odd col pad
    __shared__ float4 wb[22][33];   // W-blurred 22 x 32, odd col pad

    const int tid = threadIdx.x;
    const size_t nbase = (size_t)n * DIM * SLICE;
    const float4 z = make_float4(0.f, 0.f, 0.f, 0.f);

    // ---- stage constants: 836 halo f4 over 256 threads (<=4 slots) ----
    int  soff[4], rbidx[4];
    bool sok[4];
    #pragma unroll
    for (int s = 0; s < 4; ++s) {
        const int i = tid + 256 * s;
        const bool has = (i < RAWN);
        const int rr = has ? (i / 38) : 0, cc = has ? (i % 38) : 0;
        const int gh = h0 + rr - 3, gw = w0 + cc - 3;
        const bool ok = has && gh >= 0 && gh < DIM && gw >= 0 && gw < DIM;
        soff[s]  = ok ? (gh * DIM + gw) : 0;
        sok[s]   = ok;
        rbidx[s] = rr * 39 + cc;
    }
    const bool shas3 = (tid + 768 < RAWN);

    // ---- W-blur workers: 176 = 22 rows x 8 groups of 4 cols ----
    const bool isW = (tid < 176);
    const int wr  = tid >> 3;        // 0..21
    const int wc0 = (tid & 7) * 4;   // 0,4,...,28

    // ---- H-blur: 256 threads = 8 H-pairs x 32 cols ----
    const int hp = tid >> 5;         // 0..7 -> output rows 2hp, 2hp+1
    const int lw = tid & 31;         // 0..31

    // output pointers for the two owned rows, advanced by increment
    float4* outp0 = out + nbase + ((size_t)d0 * DIM + (h0 + 2 * hp)) * DIM + (w0 + lw);
    float4* outp1 = outp0 + DIM;

    const float4* inp = in + nbase;

    float4 pf0, pf1, pf2, pf3;
    float4 a0 = z, a1 = z, a2 = z, a3 = z, a4 = z, a5 = z, a6 = z;  // ring row 2hp
    float4 b0 = z, b1 = z, b2 = z, b3 = z, b4 = z, b5 = z, b6 = z;  // ring row 2hp+1

#define PREFETCH(DSL)                                                        \
    do {                                                                     \
        const int _d = (DSL);                                                \
        const bool _inr = (_d >= 0) && (_d < DIM);                           \
        const float4* _s = inp + (size_t)(_inr ? _d : 0) * SLICE;            \
        pf0 = (_inr && sok[0]) ? _s[soff[0]] : z;                            \
        pf1 = (_inr && sok[1]) ? _s[soff[1]] : z;                            \
        pf2 = (_inr && sok[2]) ? _s[soff[2]] : z;                            \
        pf3 = (_inr && sok[3]) ? _s[soff[3]] : z;                            \
    } while (0)

    PREFETCH(d0 - 3);

    #pragma unroll 4
    for (int k = 0; k < CHUNK + 6; ++k) {      // 16 iterations, 4 | 16
        const int din = d0 - 3 + k;

        // 1) commit prefetched slice into raw (prev W-blur reads of raw
        //    drained at previous iteration's barrier B -> single buf safe)
        {
            float4* rb = &raw[0][0];
            rb[rbidx[0]] = pf0;
            rb[rbidx[1]] = pf1;
            rb[rbidx[2]] = pf2;
            if (shas3) rb[rbidx[3]] = pf3;
        }

        // 2) issue next slice's loads; in flight across both barriers
        if (k < CHUNK + 5) PREFETCH(din + 1);

        lds_barrier();  // A: raw visible; prev H-blur reads of wb drained

        // 3) W-blur: 176 workers, 10 raw reads -> 4 wb outputs each
        if (isW) {
            float4 rv0 = raw[wr][wc0 + 0];
            float4 rv1 = raw[wr][wc0 + 1];
            float4 rv2 = raw[wr][wc0 + 2];
            float4 rv3 = raw[wr][wc0 + 3];
            float4 rv4 = raw[wr][wc0 + 4];
            float4 rv5 = raw[wr][wc0 + 5];
            float4 rv6 = raw[wr][wc0 + 6];
            float4 rv7 = raw[wr][wc0 + 7];
            float4 rv8 = raw[wr][wc0 + 8];
            float4 rv9 = raw[wr][wc0 + 9];
            wb[wr][wc0 + 0] = blur7(rv0, rv1, rv2, rv3, rv4, rv5, rv6);
            wb[wr][wc0 + 1] = blur7(rv1, rv2, rv3, rv4, rv5, rv6, rv7);
            wb[wr][wc0 + 2] = blur7(rv2, rv3, rv4, rv5, rv6, rv7, rv8);
            wb[wr][wc0 + 3] = blur7(rv3, rv4, rv5, rv6, rv7, rv8, rv9);
        }

        lds_barrier();  // B: wb visible; raw reads drained (next top rewrites)

        // 4) H-blur pair: 8 wb reads -> 2 new ring values (shift renamed
        //    away by the unroll)
        {
            float4 c0 = wb[2 * hp + 0][lw];
            float4 c1 = wb[2 * hp + 1][lw];
            float4 c2 = wb[2 * hp + 2][lw];
            float4 c3 = wb[2 * hp + 3][lw];
            float4 c4 = wb[2 * hp + 4][lw];
            float4 c5 = wb[2 * hp + 5][lw];
            float4 c6 = wb[2 * hp + 6][lw];
            float4 c7 = wb[2 * hp + 7][lw];
            float4 va = blur7(c0, c1, c2, c3, c4, c5, c6);
            float4 vb = blur7(c1, c2, c3, c4, c5, c6, c7);
            a0 = a1; a1 = a2; a2 = a3; a3 = a4; a4 = a5; a5 = a6; a6 = va;
            b0 = b1; b1 = b2; b2 = b3; b3 = b4; b4 = b5; b5 = b6; b6 = vb;
        }

        // 5) emit output for dout = d0 + k - 6 once the ring is primed
        if (k >= 6) {
            float4 oa = blur7(a0, a1, a2, a3, a4, a5, a6);
            float4 ob = blur7(b0, b1, b2, b3, b4, b5, b6);
            *outp0 = oa;
            *outp1 = ob;
            outp0 += SLICE;
            outp1 += SLICE;
        }
    }
#undef PREFETCH
}

extern "C" void kernel_launch(void* const* d_in, const int* in_sizes, int n_in,
                              void* d_out, int out_size, void* d_ws, size_t ws_size,
                              hipStream_t stream) {
    const float4* in = (const float4*)d_in[0];
    float4* out = (float4*)d_out;
    gauss3d_fused<<<NBLK, 256, 0, stream>>>(in, out);
}